// Round 17
// baseline (262.919 us; speedup 1.0000x reference)
//
#include <hip/hip_runtime.h>
#include <math.h>

// Chamfer loss, B=32, N=2048, 3 used components.
// R17 = R13's main (16x16x32 MFMA, full bf16-split, passed absmax 0.0) with:
//  (1) NO launch-bounds occupancy pin (R15->R16 proved (256,4) forces a
//      64-VGPR split + scratch spill; unpinned -> 128 VGPR, clean counters),
//  (2) the sum kernel FUSED via threadfence-reduction: per-batch counters in
//      zero-init __device__ memory (claimer resets them -> graph-replay safe),
//      64th block of each batch reduces that batch's partials (~140KB, L2),
//      writes ws_sum[b]; 32nd batch-finisher folds 32 sums, plain-stores out
//      (single writer -> no out-init, no memsets, ONE dispatch total).
// Slot map (k-permutation-robust; A,B share the (group,slot)->k map):
//   g0: A=[phx,phy,phz, plx,ply,plz, x2h,x2l] B=[ghx,ghy,ghz, glx,gly,glz, 1,1]
//   g1: A=[phx,phy,phz, 1,1, 0,0,0]           B=[glx,gly,glz, y2h,y2l, 0,0,0]
//   g2: A=[plx,ply,plz, 0..]                  B=[ghx,ghy,ghz, 0..]
//   g3: A=0
// C/D layout (m89/m91): col=lane&15, row=(lane>>4)*4+reg.
// Block = 128 rows x 512 cols, grid (16,4,32) = 2048 blocks; partials
// ws_row[b][bi][jc][128] + ws_col[b][jc][bi][512], exact single-writer.

#define NPTS   2048
#define NBATCH 32
#define BROWS  128
#define BCOLS  512
#define NBI    (NPTS / BROWS)          // 16
#define NJC    (NPTS / BCOLS)          // 4
#define BLKS_PER_BATCH (NBI * NJC)     // 64
#define WS_ROW_FLOATS ((size_t)NBATCH * NBI * NJC * BROWS)   // 262144
#define WS_COL_FLOATS ((size_t)NBATCH * NJC * NBI * BCOLS)   // 1048576
#define EPSF   1e-16f
#define BIGF   3.4e38f
#define ONEBF  0x3F80u                 // bf16 1.0

typedef __attribute__((ext_vector_type(8))) short bf16x8;
typedef __attribute__((ext_vector_type(4))) float f32x4;
typedef __attribute__((ext_vector_type(4))) unsigned int u32x4;

__device__ unsigned int g_cnt[NBATCH];   // zero-init; claimer resets -> replay-safe
__device__ unsigned int g_cnt2;

__device__ __forceinline__ float min3f(float a, float b, float c) {
    return fminf(fminf(a, b), c);      // -> v_min3_f32
}
__device__ __forceinline__ unsigned short bf16_rne(float f) {
    unsigned int u = __float_as_uint(f);
    return (unsigned short)((u + 0x7FFFu + ((u >> 16) & 1u)) >> 16);
}
__device__ __forceinline__ float bf16_f32(unsigned short h) {
    return __uint_as_float(((unsigned int)h) << 16);
}

__global__ __launch_bounds__(256) void chamfer_mfma_kernel(
    const float* __restrict__ P, const float* __restrict__ Q,
    float* __restrict__ ws, float* __restrict__ out)
{
    __shared__ u32x4        sB0[BCOLS];   // B-frag group0 (8 KB)
    __shared__ u32x4        sB1[BCOLS];   // B-frag group1 (8 KB)
    __shared__ u32x4        sB2[BCOLS];   // B-frag group2 (8 KB)
    __shared__ unsigned int scol[BCOLS];  // col-min, uint-cast (2 KB)
    __shared__ float        srow[BROWS];  // row-min funnel (0.5 KB)
    __shared__ float        rbuf[4];
    __shared__ unsigned int sclaim, sfin;

    const int tid  = threadIdx.x;
    const int lane = tid & 63;
    const int wv   = tid >> 6;
    const int c15  = lane & 15;        // col-in-tile / row-in-tile
    const int g    = lane >> 4;        // k slot-group 0..3
    const int bi   = blockIdx.x;       // 128-row chunk
    const int jc   = blockIdx.y;       // 512-col chunk
    const int b    = blockIdx.z;       // batch

    // ---- stage B frags: 2 cols/thread
    {
        const float4* Qb = (const float4*)Q + (size_t)b * NPTS + jc * BCOLS;
        #pragma unroll
        for (int s = 0; s < 2; ++s) {
            int c = tid + 256 * s;
            float4 qv = Qb[c];
            float gx = -2.f * qv.y, gy = -2.f * qv.z, gz = -2.f * qv.w;
            unsigned short hx = bf16_rne(gx), hy = bf16_rne(gy), hz = bf16_rne(gz);
            unsigned short lx = bf16_rne(gx - bf16_f32(hx));
            unsigned short ly = bf16_rne(gy - bf16_f32(hy));
            unsigned short lz = bf16_rne(gz - bf16_f32(hz));
            float y2 = fmaf(qv.y, qv.y, fmaf(qv.z, qv.z, qv.w * qv.w));
            unsigned short y2h = bf16_rne(y2);
            unsigned short y2l = bf16_rne(y2 - bf16_f32(y2h));
            sB0[c] = (u32x4){ (unsigned)hx | ((unsigned)hy << 16),
                              (unsigned)hz | ((unsigned)lx << 16),
                              (unsigned)ly | ((unsigned)lz << 16),
                              ONEBF | (ONEBF << 16) };
            sB1[c] = (u32x4){ (unsigned)lx | ((unsigned)ly << 16),
                              (unsigned)lz | ((unsigned)y2h << 16),
                              (unsigned)y2l, 0u };
            sB2[c] = (u32x4){ (unsigned)hx | ((unsigned)hy << 16),
                              (unsigned)hz, 0u, 0u };
            scol[c] = 0x7F7F7F7Fu;
        }
    }

    // ---- A frags for my 2 rows (MFMA0: wave rows 0-15, MFMA1: 16-31)
    bf16x8 afrag0, afrag1;
    {
        const float4* Pb = (const float4*)P + (size_t)b * NPTS
                         + bi * BROWS + wv * 32;
        #pragma unroll
        for (int h = 0; h < 2; ++h) {
            float4 pv = Pb[h * 16 + c15];
            float x = pv.y, y = pv.z, z = pv.w;
            unsigned short hx = bf16_rne(x), hy = bf16_rne(y), hz = bf16_rne(z);
            unsigned short lx = bf16_rne(x - bf16_f32(hx));
            unsigned short ly = bf16_rne(y - bf16_f32(hy));
            unsigned short lz = bf16_rne(z - bf16_f32(hz));
            float x2 = fmaf(x, x, fmaf(y, y, z * z));
            unsigned short x2h = bf16_rne(x2);
            unsigned short x2l = bf16_rne(x2 - bf16_f32(x2h));
            u32x4 a;
            if (g == 0)
                a = (u32x4){ (unsigned)hx | ((unsigned)hy << 16),
                             (unsigned)hz | ((unsigned)lx << 16),
                             (unsigned)ly | ((unsigned)lz << 16),
                             (unsigned)x2h | ((unsigned)x2l << 16) };
            else if (g == 1)
                a = (u32x4){ (unsigned)hx | ((unsigned)hy << 16),
                             (unsigned)hz | (ONEBF << 16),
                             ONEBF, 0u };
            else if (g == 2)
                a = (u32x4){ (unsigned)lx | ((unsigned)ly << 16),
                             (unsigned)lz, 0u, 0u };
            else
                a = (u32x4){ 0u, 0u, 0u, 0u };
            if (h == 0) afrag0 = __builtin_bit_cast(bf16x8, a);
            else        afrag1 = __builtin_bit_cast(bf16x8, a);
        }
    }
    __syncthreads();

    // ---- main loop: 32 col-tiles of 16; D = full d2 (C = 0)
    const u32x4* bbase = (g == 0) ? sB0 : (g == 1) ? sB1 : sB2;  // g3: A=0
    const f32x4 cz = {0.f, 0.f, 0.f, 0.f};
    float ra0[4], ra1[4];
    #pragma unroll
    for (int r = 0; r < 4; ++r) { ra0[r] = BIGF; ra1[r] = BIGF; }

    #pragma unroll 2
    for (int t = 0; t < BCOLS / 16; ++t) {
        bf16x8 bfrag = __builtin_bit_cast(bf16x8, bbase[t * 16 + c15]);
        f32x4 d0 = __builtin_amdgcn_mfma_f32_16x16x32_bf16(afrag0, bfrag, cz, 0, 0, 0);
        f32x4 d1 = __builtin_amdgcn_mfma_f32_16x16x32_bf16(afrag1, bfrag, cz, 0, 0, 0);
        #pragma unroll
        for (int r = 0; r < 4; ++r) {
            ra0[r] = fminf(ra0[r], d0[r]);
            ra1[r] = fminf(ra1[r], d1[r]);
        }
        float m = min3f(min3f(d0[0], d0[1], d0[2]),
                        min3f(d0[3], d1[0], d1[1]),
                        fminf(d1[2], d1[3]));
        m = fminf(m, __shfl_xor(m, 16));
        m = fminf(m, __shfl_xor(m, 32));
        if (lane < 16)
            atomicMin(&scol[t * 16 + lane], __float_as_uint(fmaxf(m, 0.f)));
    }

    // ---- row epilogue: min over cols = reduce across c15 bits
    #pragma unroll
    for (int r = 0; r < 4; ++r) {
        float v0 = ra0[r], v1 = ra1[r];
        v0 = fminf(v0, __shfl_xor(v0, 1)); v1 = fminf(v1, __shfl_xor(v1, 1));
        v0 = fminf(v0, __shfl_xor(v0, 2)); v1 = fminf(v1, __shfl_xor(v1, 2));
        v0 = fminf(v0, __shfl_xor(v0, 4)); v1 = fminf(v1, __shfl_xor(v1, 4));
        v0 = fminf(v0, __shfl_xor(v0, 8)); v1 = fminf(v1, __shfl_xor(v1, 8));
        if (c15 == 0) {                    // lanes 0,16,32,48: row g*4+r
            srow[wv * 32 + g * 4 + r]      = v0;
            srow[wv * 32 + 16 + g * 4 + r] = v1;
        }
    }
    __syncthreads();

    // ---- single-writer global partials (coalesced)
    if (tid < BROWS)
        ws[(((size_t)b * NBI + bi) * NJC + jc) * BROWS + tid] = srow[tid];
    {
        float* cb = ws + WS_ROW_FLOATS
                  + (((size_t)b * NJC + jc) * NBI + bi) * BCOLS;
        #pragma unroll
        for (int s = 0; s < 2; ++s) {
            int c = tid + 256 * s;
            cb[c] = __uint_as_float(scol[c]);   // clamped >= 0 already
        }
    }

    // ---- fused finisher: last block of batch b reduces the batch
    __threadfence();                       // each thread releases its stores
    __syncthreads();
    if (tid == 0) {
        unsigned int old = atomicAdd(&g_cnt[b], 1u);
        sclaim = (old == BLKS_PER_BATCH - 1) ? 1u : 0u;
        if (sclaim) g_cnt[b] = 0;          // reset for next graph replay
    }
    __syncthreads();
    if (sclaim) {
        __threadfence();                   // acquire other blocks' partials
        float s = 0.f;
        for (int rr = tid; rr < NPTS; rr += 256) {
            int rbi = rr >> 7, rl = rr & 127;
            const float* rb = ws + (((size_t)b * NBI + rbi) * NJC) * BROWS + rl;
            float v = BIGF;
            #pragma unroll
            for (int j = 0; j < NJC; ++j) v = fminf(v, rb[(size_t)j * BROWS]);
            s += sqrtf(fmaxf(v, 0.f) + EPSF);
        }
        for (int cc = tid; cc < NPTS; cc += 256) {
            int cjc = cc >> 9, cl = cc & 511;
            const float* cb = ws + WS_ROW_FLOATS
                            + (((size_t)b * NJC + cjc) * NBI) * BCOLS + cl;
            float v = BIGF;
            #pragma unroll
            for (int j = 0; j < NBI; ++j) v = fminf(v, cb[(size_t)j * BCOLS]);
            s += sqrtf(fmaxf(v, 0.f) + EPSF);
        }
        #pragma unroll
        for (int off = 32; off > 0; off >>= 1) s += __shfl_down(s, off);
        if ((tid & 63) == 0) rbuf[tid >> 6] = s;
        __syncthreads();
        float* wsum = ws + WS_ROW_FLOATS + WS_COL_FLOATS;
        if (tid == 0) {
            wsum[b] = 0.5f * ((rbuf[0] + rbuf[1]) + (rbuf[2] + rbuf[3]));
            __threadfence();
            unsigned int old2 = atomicAdd(&g_cnt2, 1u);
            sfin = (old2 == NBATCH - 1) ? 1u : 0u;
            if (sfin) g_cnt2 = 0;          // reset for next graph replay
        }
        __syncthreads();
        if (sfin) {                        // globally-last batch finisher
            __threadfence();
            if (tid < 64) {
                float v = (tid < NBATCH) ? wsum[tid] : 0.f;
                #pragma unroll
                for (int off = 32; off > 0; off >>= 1) v += __shfl_down(v, off);
                if (tid == 0) *out = v;    // single writer, no init needed
            }
        }
    }
}

extern "C" void kernel_launch(void* const* d_in, const int* in_sizes, int n_in,
                              void* d_out, int out_size, void* d_ws, size_t ws_size,
                              hipStream_t stream) {
    const float* P = (const float*)d_in[0];   // p[0] = first 32*2048*4 floats
    const float* Q = (const float*)d_in[1];
    float* out = (float*)d_out;
    float* ws  = (float*)d_ws;                // uses ~5.0 MiB

    dim3 grid(NBI, NJC, NBATCH);              // 16 x 4 x 32 = 2048 blocks
    chamfer_mfma_kernel<<<grid, 256, 0, stream>>>(P, Q, ws, out);
}

// Round 18
// 81.627 us; speedup vs baseline: 3.2210x; 3.2210x over previous
//
#include <hip/hip_runtime.h>
#include <math.h>

// Chamfer loss, B=32, N=2048, 3 used components.
// R18: max-occupancy config never yet tested. Evidence chain:
//  - latency-bound regime (both pipes idle in every clean profile);
//  - pinned (256,4) VGPR-64 mains (R10/R13) = ~30us beat unpinned VGPR-128
//    4-blocks/CU (R16) = 43us -> occupancy is the lever;
//  - R13's residency capped by LDS (26.5KB -> 6 blocks/CU), not VGPR;
//  - R15 (BCOLS=256, LDS 13.8KB) had the right geometry but spilled 18 regs
//    from the colL[16] hoist (80MB scratch WRITE).
// Fix: in-loop col reduce (R13 body, fits 64 VGPR) + BCOLS=256 + pin
// (256,8) -> 8 blocks/CU x 4 waves = 32 waves/CU (FULL occupancy).
// Slot map / bf16 full-split / C=0 (k-permutation-robust, passed absmax 0):
//   g0: A=[phx,phy,phz, plx,ply,plz, x2h,x2l] B=[ghx,ghy,ghz, glx,gly,glz, 1,1]
//   g1: A=[phx,phy,phz, 1,1, 0,0,0]           B=[glx,gly,glz, y2h,y2l, 0,0,0]
//   g2: A=[plx,ply,plz, 0..]                  B=[ghx,ghy,ghz, 0..]
//   g3: A=0
// C/D layout (m89/m91): col=lane&15, row=(lane>>4)*4+reg.
// Grid (16,8,32)=4096 blocks; ws_row[b][bi][jc][128] 2MB +
// ws_col[b][jc][bi][256] 2MB, exact single-writer (no init, no atomics in
// global). Separate sum kernel (fusion disproven in R17: device-scope
// threadfence per block = L2-writeback serialization, 217us).
// 2 dispatches, zero memsets.

#define NPTS   2048
#define NBATCH 32
#define BROWS  128
#define BCOLS  256
#define NBI    (NPTS / BROWS)          // 16
#define NJC    (NPTS / BCOLS)          // 8
#define WS_ROW_FLOATS ((size_t)NBATCH * NBI * NJC * BROWS)   // 524288 floats
#define EPSF   1e-16f
#define BIGF   3.4e38f
#define ONEBF  0x3F80u                 // bf16 1.0

typedef __attribute__((ext_vector_type(8))) short bf16x8;
typedef __attribute__((ext_vector_type(4))) float f32x4;
typedef __attribute__((ext_vector_type(4))) unsigned int u32x4;

__device__ __forceinline__ float min3f(float a, float b, float c) {
    return fminf(fminf(a, b), c);      // -> v_min3_f32
}
__device__ __forceinline__ unsigned short bf16_rne(float f) {
    unsigned int u = __float_as_uint(f);
    return (unsigned short)((u + 0x7FFFu + ((u >> 16) & 1u)) >> 16);
}
__device__ __forceinline__ float bf16_f32(unsigned short h) {
    return __uint_as_float(((unsigned int)h) << 16);
}

__global__ __launch_bounds__(256, 8) void chamfer_mfma_kernel(
    const float* __restrict__ P, const float* __restrict__ Q,
    float* __restrict__ ws, float* __restrict__ out)
{
    __shared__ u32x4        sB0[BCOLS];   // B-frag group0 (4 KB)
    __shared__ u32x4        sB1[BCOLS];   // B-frag group1 (4 KB)
    __shared__ u32x4        sB2[BCOLS];   // B-frag group2 (4 KB)
    __shared__ unsigned int scol[BCOLS];  // col-min, uint-cast (1 KB)
    __shared__ float        srow[BROWS];  // row-min funnel (0.5 KB)

    const int tid  = threadIdx.x;
    const int lane = tid & 63;
    const int wv   = tid >> 6;
    const int c15  = lane & 15;        // col-in-tile / row-in-tile
    const int g    = lane >> 4;        // k slot-group 0..3
    const int bi   = blockIdx.x;       // 128-row chunk
    const int jc   = blockIdx.y;       // 256-col chunk
    const int b    = blockIdx.z;       // batch

    if (bi == 0 && jc == 0 && b == 0 && tid == 0) *out = 0.f;

    // ---- stage B frags: 1 col/thread
    {
        const float4* Qb = (const float4*)Q + (size_t)b * NPTS + jc * BCOLS;
        int c = tid;
        float4 qv = Qb[c];
        float gx = -2.f * qv.y, gy = -2.f * qv.z, gz = -2.f * qv.w;
        unsigned short hx = bf16_rne(gx), hy = bf16_rne(gy), hz = bf16_rne(gz);
        unsigned short lx = bf16_rne(gx - bf16_f32(hx));
        unsigned short ly = bf16_rne(gy - bf16_f32(hy));
        unsigned short lz = bf16_rne(gz - bf16_f32(hz));
        float y2 = fmaf(qv.y, qv.y, fmaf(qv.z, qv.z, qv.w * qv.w));
        unsigned short y2h = bf16_rne(y2);
        unsigned short y2l = bf16_rne(y2 - bf16_f32(y2h));
        sB0[c] = (u32x4){ (unsigned)hx | ((unsigned)hy << 16),
                          (unsigned)hz | ((unsigned)lx << 16),
                          (unsigned)ly | ((unsigned)lz << 16),
                          ONEBF | (ONEBF << 16) };
        sB1[c] = (u32x4){ (unsigned)lx | ((unsigned)ly << 16),
                          (unsigned)lz | ((unsigned)y2h << 16),
                          (unsigned)y2l, 0u };
        sB2[c] = (u32x4){ (unsigned)hx | ((unsigned)hy << 16),
                          (unsigned)hz, 0u, 0u };
        scol[c] = 0x7F7F7F7Fu;
    }

    // ---- A frags for my 2 rows (MFMA0: wave rows 0-15, MFMA1: 16-31)
    bf16x8 afrag0, afrag1;
    {
        const float4* Pb = (const float4*)P + (size_t)b * NPTS
                         + bi * BROWS + wv * 32;
        #pragma unroll
        for (int h = 0; h < 2; ++h) {
            float4 pv = Pb[h * 16 + c15];
            float x = pv.y, y = pv.z, z = pv.w;
            unsigned short hx = bf16_rne(x), hy = bf16_rne(y), hz = bf16_rne(z);
            unsigned short lx = bf16_rne(x - bf16_f32(hx));
            unsigned short ly = bf16_rne(y - bf16_f32(hy));
            unsigned short lz = bf16_rne(z - bf16_f32(hz));
            float x2 = fmaf(x, x, fmaf(y, y, z * z));
            unsigned short x2h = bf16_rne(x2);
            unsigned short x2l = bf16_rne(x2 - bf16_f32(x2h));
            u32x4 a;
            if (g == 0)
                a = (u32x4){ (unsigned)hx | ((unsigned)hy << 16),
                             (unsigned)hz | ((unsigned)lx << 16),
                             (unsigned)ly | ((unsigned)lz << 16),
                             (unsigned)x2h | ((unsigned)x2l << 16) };
            else if (g == 1)
                a = (u32x4){ (unsigned)hx | ((unsigned)hy << 16),
                             (unsigned)hz | (ONEBF << 16),
                             ONEBF, 0u };
            else if (g == 2)
                a = (u32x4){ (unsigned)lx | ((unsigned)ly << 16),
                             (unsigned)lz, 0u, 0u };
            else
                a = (u32x4){ 0u, 0u, 0u, 0u };
            if (h == 0) afrag0 = __builtin_bit_cast(bf16x8, a);
            else        afrag1 = __builtin_bit_cast(bf16x8, a);
        }
    }
    __syncthreads();

    // ---- main loop: 16 col-tiles of 16; in-loop col reduce (fits 64 VGPR)
    const u32x4* bbase = (g == 0) ? sB0 : (g == 1) ? sB1 : sB2;  // g3: A=0
    const f32x4 cz = {0.f, 0.f, 0.f, 0.f};
    float ra0[4], ra1[4];
    #pragma unroll
    for (int r = 0; r < 4; ++r) { ra0[r] = BIGF; ra1[r] = BIGF; }

    #pragma unroll 2
    for (int t = 0; t < BCOLS / 16; ++t) {
        bf16x8 bfrag = __builtin_bit_cast(bf16x8, bbase[t * 16 + c15]);
        f32x4 d0 = __builtin_amdgcn_mfma_f32_16x16x32_bf16(afrag0, bfrag, cz, 0, 0, 0);
        f32x4 d1 = __builtin_amdgcn_mfma_f32_16x16x32_bf16(afrag1, bfrag, cz, 0, 0, 0);
        #pragma unroll
        for (int r = 0; r < 4; ++r) {
            ra0[r] = fminf(ra0[r], d0[r]);
            ra1[r] = fminf(ra1[r], d1[r]);
        }
        float m = min3f(min3f(d0[0], d0[1], d0[2]),
                        min3f(d0[3], d1[0], d1[1]),
                        fminf(d1[2], d1[3]));
        m = fminf(m, __shfl_xor(m, 16));
        m = fminf(m, __shfl_xor(m, 32));
        if (lane < 16)
            atomicMin(&scol[t * 16 + lane], __float_as_uint(fmaxf(m, 0.f)));
    }

    // ---- row epilogue: min over cols = reduce across c15 bits
    #pragma unroll
    for (int r = 0; r < 4; ++r) {
        float v0 = ra0[r], v1 = ra1[r];
        v0 = fminf(v0, __shfl_xor(v0, 1)); v1 = fminf(v1, __shfl_xor(v1, 1));
        v0 = fminf(v0, __shfl_xor(v0, 2)); v1 = fminf(v1, __shfl_xor(v1, 2));
        v0 = fminf(v0, __shfl_xor(v0, 4)); v1 = fminf(v1, __shfl_xor(v1, 4));
        v0 = fminf(v0, __shfl_xor(v0, 8)); v1 = fminf(v1, __shfl_xor(v1, 8));
        if (c15 == 0) {                    // lanes 0,16,32,48: row g*4+r
            srow[wv * 32 + g * 4 + r]      = v0;
            srow[wv * 32 + 16 + g * 4 + r] = v1;
        }
    }
    __syncthreads();

    // ---- single-writer global partials (coalesced)
    if (tid < BROWS)
        ws[(((size_t)b * NBI + bi) * NJC + jc) * BROWS + tid] = srow[tid];
    {
        float* cb = ws + WS_ROW_FLOATS
                  + (((size_t)b * NJC + jc) * NBI + bi) * BCOLS;
        cb[tid] = __uint_as_float(scol[tid]);   // clamped >= 0 already
    }
}

__global__ __launch_bounds__(256) void chamfer_sum_kernel(
    const float* __restrict__ ws, float* __restrict__ out)
{
    __shared__ float rbuf[4];
    const int tid = threadIdx.x;
    const int i   = blockIdx.x * 256 + tid;   // 0..65535
    const int b   = i >> 11;
    const int e   = i & 2047;

    // row side: min over 8 jc partials (coalesced in rl)
    float s;
    {
        const int bi = e >> 7, rl = e & 127;
        const float* rb = ws + ((size_t)(b * NBI + bi) * NJC) * BROWS + rl;
        float v = BIGF;
        #pragma unroll
        for (int j = 0; j < NJC; ++j) v = fminf(v, rb[(size_t)j * BROWS]);
        s = sqrtf(fmaxf(v, 0.f) + EPSF);
    }
    // col side: min over 16 bi partials (coalesced in cl)
    {
        const int jcx = e >> 8, cl = e & 255;
        const float* cb = ws + WS_ROW_FLOATS
                        + ((size_t)(b * NJC + jcx) * NBI) * BCOLS + cl;
        float v = BIGF;
        #pragma unroll
        for (int j = 0; j < NBI; ++j) v = fminf(v, cb[(size_t)j * BCOLS]);
        s += sqrtf(fmaxf(v, 0.f) + EPSF);
    }

    #pragma unroll
    for (int off = 32; off > 0; off >>= 1) s += __shfl_down(s, off);
    if ((tid & 63) == 0) rbuf[tid >> 6] = s;
    __syncthreads();
    if (tid == 0)
        atomicAdd(out, 0.5f * ((rbuf[0] + rbuf[1]) + (rbuf[2] + rbuf[3])));
}

extern "C" void kernel_launch(void* const* d_in, const int* in_sizes, int n_in,
                              void* d_out, int out_size, void* d_ws, size_t ws_size,
                              hipStream_t stream) {
    const float* P = (const float*)d_in[0];   // p[0] = first 32*2048*4 floats
    const float* Q = (const float*)d_in[1];
    float* out = (float*)d_out;
    float* ws  = (float*)d_ws;                // uses 4 MiB

    dim3 grid(NBI, NJC, NBATCH);              // 16 x 8 x 32 = 4096 blocks
    chamfer_mfma_kernel<<<grid, 256, 0, stream>>>(P, Q, ws, out);
    chamfer_sum_kernel<<<256, 256, 0, stream>>>(ws, out);
}